// Round 1
// baseline (541.887 us; speedup 1.0000x reference)
//
#include <hip/hip_runtime.h>
#include <stdint.h>

// ---------------------------------------------------------------------------
// CausalSelfAttention (B=4, T=2048, C=1024, H=16, D=64) on gfx950.
// Pipeline: cast x->bf16; transpose W's to [N][K] bf16; QKV GEMM (bf16 MFMA,
// fp32 acc) scattering to (B,H,T,D); causal flash attention; proj GEMM.
// ---------------------------------------------------------------------------

typedef __attribute__((ext_vector_type(8))) __bf16 bf16x8_t;  // MFMA A/B frag
typedef __attribute__((ext_vector_type(8))) short s16x8_t;
typedef __attribute__((ext_vector_type(4))) float f32x4_t;    // MFMA C/D frag
typedef __attribute__((ext_vector_type(4))) unsigned short u16x4_t;

static __device__ __forceinline__ unsigned short f2bf(float f) {
  union { float f; unsigned u; } c; c.f = f;
  unsigned r = c.u + 0x7FFFu + ((c.u >> 16) & 1u);  // RNE
  return (unsigned short)(r >> 16);
}

// async global->LDS, 16B per lane. LDS dest is base+lane*16 (linear), which is
// exactly how per-thread tid*16 offsets lay out (guide §5 caveat).
static __device__ __forceinline__ void gload16(const void* g, void* lds) {
  __builtin_amdgcn_global_load_lds(
      (const __attribute__((address_space(1))) unsigned int*)g,
      (__attribute__((address_space(3))) unsigned int*)(uint32_t)(uintptr_t)lds,
      16, 0, 0);
}

// ---------------------------------------------------------------------------
// cast fp32 -> bf16, 4 elems/thread
__global__ __launch_bounds__(256) void k_cast_bf16(const float* __restrict__ in,
                                                   unsigned short* __restrict__ out) {
  int i = blockIdx.x * 256 + threadIdx.x;
  float4 v = ((const float4*)in)[i];
  u16x4_t r = { f2bf(v.x), f2bf(v.y), f2bf(v.z), f2bf(v.w) };
  ((u16x4_t*)out)[i] = r;
}

// W[K][N] fp32 -> Wt[N][K] bf16, 32x32 LDS tile, both sides coalesced
__global__ __launch_bounds__(256) void k_transpose_cast(const float* __restrict__ W,
                                                        unsigned short* __restrict__ Wt,
                                                        int Kd, int Nd) {
  __shared__ float tile[32][33];
  int n0 = blockIdx.x * 32, k0 = blockIdx.y * 32;
  int tx = threadIdx.x, ty = threadIdx.y;
#pragma unroll
  for (int i = 0; i < 4; ++i)
    tile[ty + 8 * i][tx] = W[(size_t)(k0 + ty + 8 * i) * Nd + n0 + tx];
  __syncthreads();
#pragma unroll
  for (int i = 0; i < 4; ++i)
    Wt[(size_t)(n0 + ty + 8 * i) * Kd + k0 + tx] = f2bf(tile[tx][ty + 8 * i]);
}

// ---------------------------------------------------------------------------
// m97-structure GEMM core: 128x128 tile, BK=32, 4 waves (2x2), 4x4 frags.
// A[M][K], Bt[N][K] row-major bf16 (ushort bits). acc[m][n] over K.
static __device__ __forceinline__ void gemm128_core(
    const unsigned short* __restrict__ A, const unsigned short* __restrict__ Bt,
    int Kdim, int rowBase, int colBase,
    unsigned short* As, unsigned short* Bs, f32x4_t acc[4][4]) {
  const int tid = threadIdx.x;
  const int lane = tid & 63;
  const int wr = (tid >> 7) & 1;
  const int wc = (tid >> 6) & 1;
  // staging: thread t copies 16B: row=t/4 (+64 for chunk1), kbyte=(t&3)*16
  const unsigned short* aSrc = A + (size_t)(rowBase + (tid >> 2)) * Kdim + (tid & 3) * 8;
  const unsigned short* bSrc = Bt + (size_t)(colBase + (tid >> 2)) * Kdim + (tid & 3) * 8;
  unsigned short* aDst0 = As + tid * 8;
  unsigned short* aDst1 = As + tid * 8 + 2048;
  unsigned short* bDst0 = Bs + tid * 8;
  unsigned short* bDst1 = Bs + tid * 8 + 2048;
  const int ar = wr * 64 + (lane & 15);
  const int br = wc * 64 + (lane & 15);
  const int kk = (lane >> 4) * 8;
  for (int k0 = 0; k0 < Kdim; k0 += 32) {
    gload16(aSrc + k0, aDst0);
    gload16(aSrc + k0 + 64 * Kdim, aDst1);
    gload16(bSrc + k0, bDst0);
    gload16(bSrc + k0 + 64 * Kdim, bDst1);
    __syncthreads();  // drains vmcnt before barrier (compiler-inserted)
    bf16x8_t af[4], bfr[4];
#pragma unroll
    for (int m = 0; m < 4; ++m) af[m] = *(const bf16x8_t*)&As[(ar + m * 16) * 32 + kk];
#pragma unroll
    for (int n = 0; n < 4; ++n) bfr[n] = *(const bf16x8_t*)&Bs[(br + n * 16) * 32 + kk];
#pragma unroll
    for (int m = 0; m < 4; ++m)
#pragma unroll
      for (int n = 0; n < 4; ++n)
        acc[m][n] = __builtin_amdgcn_mfma_f32_16x16x32_bf16(af[m], bfr[n], acc[m][n], 0, 0, 0);
    __syncthreads();
  }
}

// QKV GEMM: C[8192][3072] = x_bf16 @ W_qkv + b; scatter to Q/K/V (B,H,T,D) bf16
__global__ __launch_bounds__(256) void k_gemm_qkv(
    const unsigned short* __restrict__ A, const unsigned short* __restrict__ Bt,
    const float* __restrict__ bias,
    unsigned short* __restrict__ Qo, unsigned short* __restrict__ Ko,
    unsigned short* __restrict__ Vo) {
  __shared__ alignas(16) unsigned short As[128 * 32];
  __shared__ alignas(16) unsigned short Bs[128 * 32];
  f32x4_t acc[4][4];
  f32x4_t z = {0.f, 0.f, 0.f, 0.f};
#pragma unroll
  for (int m = 0; m < 4; ++m)
#pragma unroll
    for (int n = 0; n < 4; ++n) acc[m][n] = z;
  gemm128_core(A, Bt, 1024, blockIdx.y * 128, blockIdx.x * 128, As, Bs, acc);
  const int tid = threadIdx.x, lane = tid & 63;
  const int wr = (tid >> 7) & 1, wc = (tid >> 6) & 1;
#pragma unroll
  for (int n = 0; n < 4; ++n) {
    int col = blockIdx.x * 128 + wc * 64 + n * 16 + (lane & 15);
    int which = col >> 10;                 // 0=q 1=k 2=v
    int h = (col >> 6) & 15;
    int d = col & 63;
    unsigned short* dst = which == 0 ? Qo : (which == 1 ? Ko : Vo);
    float bv = bias[col];
#pragma unroll
    for (int m = 0; m < 4; ++m)
#pragma unroll
      for (int r = 0; r < 4; ++r) {
        int row = blockIdx.y * 128 + wr * 64 + m * 16 + ((lane >> 4) * 4) + r;  // = b*2048+t
        int b = row >> 11, t = row & 2047;
        dst[(size_t)((b * 16 + h) * 2048 + t) * 64 + d] = f2bf(acc[m][n][r] + bv);
      }
  }
}

// proj GEMM: out fp32 [8192][1024] = attO_bf16 @ W_proj + b
__global__ __launch_bounds__(256) void k_gemm_proj(
    const unsigned short* __restrict__ A, const unsigned short* __restrict__ Bt,
    const float* __restrict__ bias, float* __restrict__ out) {
  __shared__ alignas(16) unsigned short As[128 * 32];
  __shared__ alignas(16) unsigned short Bs[128 * 32];
  f32x4_t acc[4][4];
  f32x4_t z = {0.f, 0.f, 0.f, 0.f};
#pragma unroll
  for (int m = 0; m < 4; ++m)
#pragma unroll
    for (int n = 0; n < 4; ++n) acc[m][n] = z;
  gemm128_core(A, Bt, 1024, blockIdx.y * 128, blockIdx.x * 128, As, Bs, acc);
  const int tid = threadIdx.x, lane = tid & 63;
  const int wr = (tid >> 7) & 1, wc = (tid >> 6) & 1;
#pragma unroll
  for (int n = 0; n < 4; ++n) {
    int col = blockIdx.x * 128 + wc * 64 + n * 16 + (lane & 15);
    float bv = bias[col];
#pragma unroll
    for (int m = 0; m < 4; ++m)
#pragma unroll
      for (int r = 0; r < 4; ++r) {
        int row = blockIdx.y * 128 + wr * 64 + m * 16 + ((lane >> 4) * 4) + r;
        out[(size_t)row * 1024 + col] = acc[m][n][r] + bv;
      }
  }
}

// ---------------------------------------------------------------------------
// causal flash attention. Block = (qtile of 64 rows, bh). 4 waves, each owns
// 16 q-rows, loops its own causal range (no block barriers). KB=32.
__global__ __launch_bounds__(256) void k_attn(const unsigned short* __restrict__ Q,
                                              const unsigned short* __restrict__ K,
                                              const unsigned short* __restrict__ V,
                                              unsigned short* __restrict__ O) {
  __shared__ alignas(16) unsigned short Plds[4][16 * 32];  // per-wave P buffer
  const int bh = blockIdx.y;
  const int q0 = blockIdx.x * 64;
  const int tid = threadIdx.x;
  const int lane = tid & 63;
  const int w = tid >> 6;
  const unsigned short* Qh = Q + (size_t)bh * 2048 * 64;
  const unsigned short* Kh = K + (size_t)bh * 2048 * 64;
  const unsigned short* Vh = V + (size_t)bh * 2048 * 64;
  const int qrow = q0 + w * 16;
  const int l15 = lane & 15, lhi = lane >> 4;

  bf16x8_t qf[2];
#pragma unroll
  for (int kk = 0; kk < 2; ++kk)
    qf[kk] = *(const bf16x8_t*)&Qh[(size_t)(qrow + l15) * 64 + kk * 32 + lhi * 8];

  f32x4_t z = {0.f, 0.f, 0.f, 0.f};
  f32x4_t o[4];
#pragma unroll
  for (int dt = 0; dt < 4; ++dt) o[dt] = z;
  float m_r[4], l_r[4];
  int rowg[4];
#pragma unroll
  for (int r = 0; r < 4; ++r) { m_r[r] = -1e30f; l_r[r] = 0.f; rowg[r] = qrow + lhi * 4 + r; }

  const int kv_end = qrow + 16;  // causal: this wave's rows need kv <= qrow+15
  for (int kv0 = 0; kv0 < kv_end; kv0 += 32) {
    // S = Q K^T  (C-layout: row=lhi*4+r (q), col=l15 (kv))
    f32x4_t s[2]; s[0] = z; s[1] = z;
#pragma unroll
    for (int nt = 0; nt < 2; ++nt)
#pragma unroll
      for (int kk = 0; kk < 2; ++kk) {
        bf16x8_t kf = *(const bf16x8_t*)&Kh[(size_t)(kv0 + nt * 16 + l15) * 64 + kk * 32 + lhi * 8];
        s[nt] = __builtin_amdgcn_mfma_f32_16x16x32_bf16(qf[kk], kf, s[nt], 0, 0, 0);
      }
    float p[2][4], mnew[4], resc[4];
#pragma unroll
    for (int r = 0; r < 4; ++r) {
#pragma unroll
      for (int nt = 0; nt < 2; ++nt) {
        float v = s[nt][r] * 0.125f;                 // 1/sqrt(64)
        int cg = kv0 + nt * 16 + l15;
        if (cg > rowg[r]) v = -1e30f;                // causal mask
        s[nt][r] = v;
      }
      float t = fmaxf(s[0][r], s[1][r]);             // row max over 16 lanes
      t = fmaxf(t, __shfl_xor(t, 1));
      t = fmaxf(t, __shfl_xor(t, 2));
      t = fmaxf(t, __shfl_xor(t, 4));
      t = fmaxf(t, __shfl_xor(t, 8));
      mnew[r] = fmaxf(m_r[r], t);
      resc[r] = __expf(m_r[r] - mnew[r]);            // first tile: exp(-1e30-m)=0
      float a0 = __expf(s[0][r] - mnew[r]);
      float a1 = __expf(s[1][r] - mnew[r]);
      p[0][r] = a0; p[1][r] = a1;
      float u = a0 + a1;                             // row sum over 16 lanes
      u += __shfl_xor(u, 1);
      u += __shfl_xor(u, 2);
      u += __shfl_xor(u, 4);
      u += __shfl_xor(u, 8);
      l_r[r] = l_r[r] * resc[r] + u;
      m_r[r] = mnew[r];
    }
#pragma unroll
    for (int dt = 0; dt < 4; ++dt)
#pragma unroll
      for (int r = 0; r < 4; ++r) o[dt][r] *= resc[r];
    // P: C-layout -> A-layout via per-wave LDS (16x32 bf16)
#pragma unroll
    for (int nt = 0; nt < 2; ++nt)
#pragma unroll
      for (int r = 0; r < 4; ++r)
        Plds[w][(lhi * 4 + r) * 32 + nt * 16 + l15] = f2bf(p[nt][r]);
    asm volatile("s_waitcnt lgkmcnt(0)" ::: "memory");  // wave-local write->read
    bf16x8_t pf = *(const bf16x8_t*)&Plds[w][l15 * 32 + lhi * 8];
    // O += P V : B-frag of V gathered column-wise from global (L2-resident)
#pragma unroll
    for (int dt = 0; dt < 4; ++dt) {
      s16x8_t vtmp;
#pragma unroll
      for (int j = 0; j < 8; ++j)
        vtmp[j] = (short)Vh[(size_t)(kv0 + lhi * 8 + j) * 64 + dt * 16 + l15];
      bf16x8_t vf = __builtin_bit_cast(bf16x8_t, vtmp);
      o[dt] = __builtin_amdgcn_mfma_f32_16x16x32_bf16(pf, vf, o[dt], 0, 0, 0);
    }
  }
  const int b = bh >> 4, h = bh & 15;
#pragma unroll
  for (int dt = 0; dt < 4; ++dt)
#pragma unroll
    for (int r = 0; r < 4; ++r) {
      float val = o[dt][r] / l_r[r];
      O[(size_t)(b * 2048 + rowg[r]) * 1024 + h * 64 + dt * 16 + l15] = f2bf(val);
    }
}

// ---------------------------------------------------------------------------
extern "C" void kernel_launch(void* const* d_in, const int* in_sizes, int n_in,
                              void* d_out, int out_size, void* d_ws, size_t ws_size,
                              hipStream_t stream) {
  const float* x     = (const float*)d_in[0];  // (4,2048,1024)
  const float* Wqkv  = (const float*)d_in[1];  // (1024,3072)
  const float* bqkv  = (const float*)d_in[2];  // (3072,)
  const float* Wproj = (const float*)d_in[3];  // (1024,1024)
  const float* bproj = (const float*)d_in[4];  // (1024,)
  float* out = (float*)d_out;                  // (4,2048,1024) fp32

  // workspace layout (bytes): needs 92,274,688 B (~88 MiB)
  char* ws = (char*)d_ws;
  unsigned short* xb     = (unsigned short*)(ws);                    // 16 MiB
  unsigned short* wqkvT  = (unsigned short*)(ws + 16777216);         // 6 MiB  [3072][1024]
  unsigned short* wprojT = (unsigned short*)(ws + 23068672);         // 2 MiB  [1024][1024]
  unsigned short* Qb     = (unsigned short*)(ws + 25165824);         // 16 MiB (B,H,T,D)
  unsigned short* Kb     = (unsigned short*)(ws + 41943040);         // 16 MiB
  unsigned short* Vb     = (unsigned short*)(ws + 58720256);         // 16 MiB
  unsigned short* Ob     = (unsigned short*)(ws + 75497472);         // 16 MiB (B,T,C)

  k_cast_bf16<<<8192, 256, 0, stream>>>(x, xb);
  k_transpose_cast<<<dim3(96, 32), dim3(32, 8), 0, stream>>>(Wqkv, wqkvT, 1024, 3072);
  k_transpose_cast<<<dim3(32, 32), dim3(32, 8), 0, stream>>>(Wproj, wprojT, 1024, 1024);
  k_gemm_qkv<<<dim3(24, 64), 256, 0, stream>>>(xb, wqkvT, bqkv, Qb, Kb, Vb);
  k_attn<<<dim3(32, 64), 256, 0, stream>>>(Qb, Kb, Vb, Ob);
  k_gemm_proj<<<dim3(8, 64), 256, 0, stream>>>(Ob, wprojT, bproj, out);
}

// Round 4
// 341.080 us; speedup vs baseline: 1.5887x; 1.5887x over previous
//
#include <hip/hip_runtime.h>
#include <stdint.h>

// ---------------------------------------------------------------------------
// CausalSelfAttention (B=4, T=2048, C=1024, H=16, D=64) on gfx950.
// cast x->bf16; transpose W's to [N][K] bf16; QKV GEMM (bf16 MFMA) writing
// Q*0.125*log2e (B,H,T,D), K (B,H,T,D), V transposed (B,H,D,T); causal flash
// attention (KVBLK=64 LDS-staged, XOR-swizzled, dbuf); proj GEMM.
// ---------------------------------------------------------------------------

typedef __attribute__((ext_vector_type(8))) __bf16 bf16x8_t;  // MFMA A/B frag
typedef __attribute__((ext_vector_type(4))) float f32x4_t;    // MFMA C/D frag
typedef __attribute__((ext_vector_type(4))) unsigned short u16x4_t;

static __device__ __forceinline__ unsigned short f2bf(float f) {
  union { float f; unsigned u; } c; c.f = f;
  unsigned r = c.u + 0x7FFFu + ((c.u >> 16) & 1u);  // RNE
  return (unsigned short)(r >> 16);
}

// async global->LDS, 16B per lane. LDS dest must be (wave-uniform base +
// lane*16) linear; global src IS per-lane (m173) -> swizzle the source.
static __device__ __forceinline__ void gload16(const void* g, void* lds) {
  __builtin_amdgcn_global_load_lds(
      (const __attribute__((address_space(1))) unsigned int*)g,
      (__attribute__((address_space(3))) unsigned int*)(uint32_t)(uintptr_t)lds,
      16, 0, 0);
}

// ---------------------------------------------------------------------------
__global__ __launch_bounds__(256) void k_cast_bf16(const float* __restrict__ in,
                                                   unsigned short* __restrict__ out) {
  int i = blockIdx.x * 256 + threadIdx.x;
  float4 v = ((const float4*)in)[i];
  u16x4_t r = { f2bf(v.x), f2bf(v.y), f2bf(v.z), f2bf(v.w) };
  ((u16x4_t*)out)[i] = r;
}

__global__ __launch_bounds__(256) void k_transpose_cast(const float* __restrict__ W,
                                                        unsigned short* __restrict__ Wt,
                                                        int Kd, int Nd) {
  __shared__ float tile[32][33];
  int n0 = blockIdx.x * 32, k0 = blockIdx.y * 32;
  int tx = threadIdx.x, ty = threadIdx.y;
#pragma unroll
  for (int i = 0; i < 4; ++i)
    tile[ty + 8 * i][tx] = W[(size_t)(k0 + ty + 8 * i) * Nd + n0 + tx];
  __syncthreads();
#pragma unroll
  for (int i = 0; i < 4; ++i)
    Wt[(size_t)(n0 + ty + 8 * i) * Kd + k0 + tx] = f2bf(tile[tx][ty + 8 * i]);
}

// ---------------------------------------------------------------------------
// m97-structure GEMM core: 128x128 tile, BK=32, 4 waves (2x2), 4x4 frags.
static __device__ __forceinline__ void gemm128_core(
    const unsigned short* __restrict__ A, const unsigned short* __restrict__ Bt,
    int Kdim, int rowBase, int colBase,
    unsigned short* As, unsigned short* Bs, f32x4_t acc[4][4]) {
  const int tid = threadIdx.x;
  const int lane = tid & 63;
  const int wr = (tid >> 7) & 1;
  const int wc = (tid >> 6) & 1;
  const unsigned short* aSrc = A + (size_t)(rowBase + (tid >> 2)) * Kdim + (tid & 3) * 8;
  const unsigned short* bSrc = Bt + (size_t)(colBase + (tid >> 2)) * Kdim + (tid & 3) * 8;
  unsigned short* aDst0 = As + tid * 8;
  unsigned short* aDst1 = As + tid * 8 + 2048;
  unsigned short* bDst0 = Bs + tid * 8;
  unsigned short* bDst1 = Bs + tid * 8 + 2048;
  const int ar = wr * 64 + (lane & 15);
  const int br = wc * 64 + (lane & 15);
  const int kk = (lane >> 4) * 8;
  for (int k0 = 0; k0 < Kdim; k0 += 32) {
    gload16(aSrc + k0, aDst0);
    gload16(aSrc + k0 + 64 * Kdim, aDst1);
    gload16(bSrc + k0, bDst0);
    gload16(bSrc + k0 + 64 * Kdim, bDst1);
    __syncthreads();
    bf16x8_t af[4], bfr[4];
#pragma unroll
    for (int m = 0; m < 4; ++m) af[m] = *(const bf16x8_t*)&As[(ar + m * 16) * 32 + kk];
#pragma unroll
    for (int n = 0; n < 4; ++n) bfr[n] = *(const bf16x8_t*)&Bs[(br + n * 16) * 32 + kk];
#pragma unroll
    for (int m = 0; m < 4; ++m)
#pragma unroll
      for (int n = 0; n < 4; ++n)
        acc[m][n] = __builtin_amdgcn_mfma_f32_16x16x32_bf16(af[m], bfr[n], acc[m][n], 0, 0, 0);
    __syncthreads();
  }
}

// QKV GEMM. Q scaled by 0.125*log2(e) (softmax runs in base-2), V transposed.
__global__ __launch_bounds__(256) void k_gemm_qkv(
    const unsigned short* __restrict__ A, const unsigned short* __restrict__ Bt,
    const float* __restrict__ bias,
    unsigned short* __restrict__ Qo, unsigned short* __restrict__ Ko,
    unsigned short* __restrict__ Vo) {
  __shared__ alignas(16) unsigned short As[128 * 32];
  __shared__ alignas(16) unsigned short Bs[128 * 32];
  f32x4_t acc[4][4];
  f32x4_t z = {0.f, 0.f, 0.f, 0.f};
#pragma unroll
  for (int m = 0; m < 4; ++m)
#pragma unroll
    for (int n = 0; n < 4; ++n) acc[m][n] = z;
  gemm128_core(A, Bt, 1024, blockIdx.y * 128, blockIdx.x * 128, As, Bs, acc);
  const int tid = threadIdx.x, lane = tid & 63;
  const int wr = (tid >> 7) & 1, wc = (tid >> 6) & 1;
#pragma unroll
  for (int n = 0; n < 4; ++n) {
    int col = blockIdx.x * 128 + wc * 64 + n * 16 + (lane & 15);
    int which = col >> 10;                 // 0=q 1=k 2=v
    int h = (col >> 6) & 15;
    int d = col & 63;
    float bv = bias[col];
#pragma unroll
    for (int m = 0; m < 4; ++m)
#pragma unroll
      for (int r = 0; r < 4; ++r) {
        int row = blockIdx.y * 128 + wr * 64 + m * 16 + ((lane >> 4) * 4) + r;
        int b = row >> 11, t = row & 2047;
        float val = acc[m][n][r] + bv;
        if (which == 0)
          Qo[(size_t)((b * 16 + h) * 2048 + t) * 64 + d] = f2bf(val * 0.18033688011112042f);
        else if (which == 1)
          Ko[(size_t)((b * 16 + h) * 2048 + t) * 64 + d] = f2bf(val);
        else
          Vo[(size_t)((b * 16 + h) * 64 + d) * 2048 + t] = f2bf(val);
      }
  }
}

// proj GEMM: out fp32 [8192][1024] = attO_bf16 @ W_proj + b
__global__ __launch_bounds__(256) void k_gemm_proj(
    const unsigned short* __restrict__ A, const unsigned short* __restrict__ Bt,
    const float* __restrict__ bias, float* __restrict__ out) {
  __shared__ alignas(16) unsigned short As[128 * 32];
  __shared__ alignas(16) unsigned short Bs[128 * 32];
  f32x4_t acc[4][4];
  f32x4_t z = {0.f, 0.f, 0.f, 0.f};
#pragma unroll
  for (int m = 0; m < 4; ++m)
#pragma unroll
    for (int n = 0; n < 4; ++n) acc[m][n] = z;
  gemm128_core(A, Bt, 1024, blockIdx.y * 128, blockIdx.x * 128, As, Bs, acc);
  const int tid = threadIdx.x, lane = tid & 63;
  const int wr = (tid >> 7) & 1, wc = (tid >> 6) & 1;
#pragma unroll
  for (int n = 0; n < 4; ++n) {
    int col = blockIdx.x * 128 + wc * 64 + n * 16 + (lane & 15);
    float bv = bias[col];
#pragma unroll
    for (int m = 0; m < 4; ++m)
#pragma unroll
      for (int r = 0; r < 4; ++r) {
        int row = blockIdx.y * 128 + wr * 64 + m * 16 + ((lane >> 4) * 4) + r;
        out[(size_t)row * 1024 + col] = acc[m][n][r] + bv;
      }
  }
}

// ---------------------------------------------------------------------------
// causal flash attention. Block = 64 q-rows x bh; 4 waves own 16 q-rows each.
// KVBLK=64 staged in LDS (K row-major [kv][d], V transposed [d][kv]), both
// XOR-swizzled (byte ^= (row&7)<<4) via pre-swizzled global_load_lds sources.
// Q pre-scaled by 0.125*log2e -> softmax in base-2 (v_exp_f32 native).
__global__ __launch_bounds__(256) void k_attn(const unsigned short* __restrict__ Q,
                                              const unsigned short* __restrict__ K,
                                              const unsigned short* __restrict__ Vt,
                                              unsigned short* __restrict__ O) {
  __shared__ alignas(16) unsigned short KT[2][4096];  // [kv 64][d 64] swizzled
  __shared__ alignas(16) unsigned short VT[2][4096];  // [d 64][kv 64] swizzled
  __shared__ alignas(16) unsigned short PL[4][1024];  // per-wave P [q 16][kv 64] swizzled
  const int flat = blockIdx.x;
  const int bx = 31 - (flat >> 6);       // heavy diagonal blocks first
  const int bh = flat & 63;              // same bh -> same XCD (64 % 8 == 0)
  const int tid = threadIdx.x;
  const int lane = tid & 63;
  const int w = tid >> 6;
  const int l15 = lane & 15, lhi = lane >> 4;
  const unsigned short* Qh = Q + (size_t)bh * 2048 * 64;
  const unsigned short* Kh = K + (size_t)bh * 2048 * 64;
  const unsigned short* Vh = Vt + (size_t)bh * 64 * 2048;
  const int qrow = bx * 64 + w * 16;
  const int ntiles = bx + 1;
  const int swr = (l15 & 7) * 8;         // read-side XOR (u16 units)

  bf16x8_t qf[2];
#pragma unroll
  for (int kk = 0; kk < 2; ++kk)
    qf[kk] = *(const bf16x8_t*)&Qh[(size_t)(qrow + l15) * 64 + kk * 32 + lhi * 8];

  f32x4_t z = {0.f, 0.f, 0.f, 0.f};
  f32x4_t o[4];
#pragma unroll
  for (int dt = 0; dt < 4; ++dt) o[dt] = z;
  float m_r[4], l_r[4];
#pragma unroll
  for (int r = 0; r < 4; ++r) { m_r[r] = -1e30f; l_r[r] = 0.f; }

  const int srow = tid >> 3;             // staging row 0..31 (+32 second half)
  const int ssw = 8 * ((tid & 7) ^ (srow & 7));  // source-side XOR (u16)
  auto STAGE = [&](int t_, int buf_) {
#pragma unroll
    for (int i = 0; i < 2; ++i) {
      const int r_ = i * 32 + srow;
      gload16(Kh + (size_t)(t_ * 64 + r_) * 64 + ssw, &KT[buf_][i * 2048 + tid * 8]);
      gload16(Vh + (size_t)r_ * 2048 + t_ * 64 + ssw, &VT[buf_][i * 2048 + tid * 8]);
    }
  };

  STAGE(0, 0);
  __syncthreads();
  for (int t = 0; t < ntiles; ++t) {
    const int buf = t & 1;
    if (t + 1 < ntiles) STAGE(t + 1, buf ^ 1);
    // --- S = Q K^T over 64 kv ---
    f32x4_t s[4];
#pragma unroll
    for (int nt = 0; nt < 4; ++nt) s[nt] = z;
#pragma unroll
    for (int nt = 0; nt < 4; ++nt) {
      const unsigned short* kr = &KT[buf][(nt * 16 + l15) * 64];
#pragma unroll
      for (int kk = 0; kk < 2; ++kk) {
        bf16x8_t kf = *(const bf16x8_t*)&kr[(kk * 32 + lhi * 8) ^ swr];
        s[nt] = __builtin_amdgcn_mfma_f32_16x16x32_bf16(qf[kk], kf, s[nt], 0, 0, 0);
      }
    }
    // --- causal mask: only the diagonal (last) tile is partial ---
    if (t == ntiles - 1) {
#pragma unroll
      for (int nt = 0; nt < 4; ++nt)
#pragma unroll
        for (int r = 0; r < 4; ++r)
          if (nt * 16 + l15 > w * 16 + lhi * 4 + r) s[nt][r] = -1e30f;
    }
    // --- online softmax (base-2; scale folded into Q) ---
    float p[4][4], resc[4];
#pragma unroll
    for (int r = 0; r < 4; ++r) {
      float t0 = fmaxf(fmaxf(s[0][r], s[1][r]), fmaxf(s[2][r], s[3][r]));
      t0 = fmaxf(t0, __shfl_xor(t0, 1));
      t0 = fmaxf(t0, __shfl_xor(t0, 2));
      t0 = fmaxf(t0, __shfl_xor(t0, 4));
      t0 = fmaxf(t0, __shfl_xor(t0, 8));
      float mnew = fmaxf(m_r[r], t0);
      resc[r] = __builtin_amdgcn_exp2f(m_r[r] - mnew);
#pragma unroll
      for (int nt = 0; nt < 4; ++nt) p[nt][r] = __builtin_amdgcn_exp2f(s[nt][r] - mnew);
      float u = (p[0][r] + p[1][r]) + (p[2][r] + p[3][r]);
      u += __shfl_xor(u, 1);
      u += __shfl_xor(u, 2);
      u += __shfl_xor(u, 4);
      u += __shfl_xor(u, 8);
      l_r[r] = l_r[r] * resc[r] + u;
      m_r[r] = mnew;
    }
#pragma unroll
    for (int dt = 0; dt < 4; ++dt)
#pragma unroll
      for (int r = 0; r < 4; ++r) o[dt][r] *= resc[r];
    // --- P: C-layout -> A-layout via per-wave swizzled LDS ---
#pragma unroll
    for (int r = 0; r < 4; ++r) {
      const int q = lhi * 4 + r;
#pragma unroll
      for (int nt = 0; nt < 4; ++nt)
        PL[w][q * 64 + ((nt * 16 + l15) ^ ((q & 7) * 8))] = f2bf(p[nt][r]);
    }
    asm volatile("s_waitcnt lgkmcnt(0)" ::: "memory");
    __builtin_amdgcn_sched_barrier(0);
    bf16x8_t pf[2];
#pragma unroll
    for (int hh = 0; hh < 2; ++hh)
      pf[hh] = *(const bf16x8_t*)&PL[w][l15 * 64 + ((hh * 32 + lhi * 8) ^ swr)];
    // --- O += P V (V from swizzled transposed LDS tile) ---
#pragma unroll
    for (int dt = 0; dt < 4; ++dt) {
      const unsigned short* vr = &VT[buf][(dt * 16 + l15) * 64];
#pragma unroll
      for (int hh = 0; hh < 2; ++hh) {
        bf16x8_t vf = *(const bf16x8_t*)&vr[(hh * 32 + lhi * 8) ^ swr];
        o[dt] = __builtin_amdgcn_mfma_f32_16x16x32_bf16(pf[hh], vf, o[dt], 0, 0, 0);
      }
    }
    __syncthreads();
  }
  const int b = bh >> 4, h = bh & 15;
#pragma unroll
  for (int r = 0; r < 4; ++r) {
    float inv = 1.0f / l_r[r];
    int rowg = qrow + lhi * 4 + r;
#pragma unroll
    for (int dt = 0; dt < 4; ++dt)
      O[(size_t)(b * 2048 + rowg) * 1024 + h * 64 + dt * 16 + l15] = f2bf(o[dt][r] * inv);
  }
}

// ---------------------------------------------------------------------------
extern "C" void kernel_launch(void* const* d_in, const int* in_sizes, int n_in,
                              void* d_out, int out_size, void* d_ws, size_t ws_size,
                              hipStream_t stream) {
  const float* x     = (const float*)d_in[0];
  const float* Wqkv  = (const float*)d_in[1];
  const float* bqkv  = (const float*)d_in[2];
  const float* Wproj = (const float*)d_in[3];
  const float* bproj = (const float*)d_in[4];
  float* out = (float*)d_out;

  char* ws = (char*)d_ws;
  unsigned short* xb     = (unsigned short*)(ws);                    // 16 MiB
  unsigned short* wqkvT  = (unsigned short*)(ws + 16777216);         // 6 MiB
  unsigned short* wprojT = (unsigned short*)(ws + 23068672);         // 2 MiB
  unsigned short* Qb     = (unsigned short*)(ws + 25165824);         // 16 MiB (B,H,T,D) *0.125*log2e
  unsigned short* Kb     = (unsigned short*)(ws + 41943040);         // 16 MiB (B,H,T,D)
  unsigned short* Vb     = (unsigned short*)(ws + 58720256);         // 16 MiB (B,H,D,T) transposed
  unsigned short* Ob     = (unsigned short*)(ws + 75497472);         // 16 MiB (B,T,C)

  k_cast_bf16<<<8192, 256, 0, stream>>>(x, xb);
  k_transpose_cast<<<dim3(96, 32), dim3(32, 8), 0, stream>>>(Wqkv, wqkvT, 1024, 3072);
  k_transpose_cast<<<dim3(32, 32), dim3(32, 8), 0, stream>>>(Wproj, wprojT, 1024, 1024);
  k_gemm_qkv<<<dim3(24, 64), 256, 0, stream>>>(xb, wqkvT, bqkv, Qb, Kb, Vb);
  k_attn<<<2048, 256, 0, stream>>>(Qb, Kb, Vb, Ob);
  k_gemm_proj<<<dim3(8, 64), 256, 0, stream>>>(Ob, wprojT, bproj, out);
}

// Round 6
// 288.746 us; speedup vs baseline: 1.8767x; 1.1812x over previous
//
#include <hip/hip_runtime.h>
#include <stdint.h>

// ---------------------------------------------------------------------------
// CausalSelfAttention (B=4, T=2048, C=1024, H=16, D=64) on gfx950.
// cast x->bf16; transpose W's to [N][K] bf16; QKV GEMM (bf16 MFMA) writing
// Q*0.125*log2e (B,H,T,D), K (B,H,T,D), V transposed (B,H,D,T); causal flash
// attention (32x32 swapped-QK^T, in-register softmax, KVBLK=64 LDS dbuf,
// XOR-swizzled, cvt_pk+permlane32_swap P-repack); proj GEMM.
// ---------------------------------------------------------------------------

typedef __attribute__((ext_vector_type(8))) __bf16 bf16x8_t;   // MFMA A/B frag
typedef __attribute__((ext_vector_type(4))) float f32x4_t;     // 16x16 C/D
typedef __attribute__((ext_vector_type(16))) float f32x16_t;   // 32x32 C/D
typedef __attribute__((ext_vector_type(4))) unsigned short u16x4_t;
typedef __attribute__((ext_vector_type(4))) unsigned int u32x4_t;

static __device__ __forceinline__ unsigned short f2bf(float f) {
  union { float f; unsigned u; } c; c.f = f;
  unsigned r = c.u + 0x7FFFu + ((c.u >> 16) & 1u);  // RNE
  return (unsigned short)(r >> 16);
}

static __device__ __forceinline__ unsigned cvt_pk_bf16(float lo, float hi) {
  unsigned r;
  asm volatile("v_cvt_pk_bf16_f32 %0, %1, %2" : "=v"(r) : "v"(lo), "v"(hi));
  return r;
}

// v_permlane32_swap_b32 a,b : a.hi32lanes <-> b.lo32lanes (both updated)
static __device__ __forceinline__ void perm32swap(unsigned& a, unsigned& b) {
  asm volatile("v_permlane32_swap_b32 %0, %1" : "+v"(a), "+v"(b));
}

static __device__ __forceinline__ f32x16_t zero16() {
  f32x16_t v;
#pragma unroll
  for (int i = 0; i < 16; ++i) v[i] = 0.f;
  return v;
}

// async global->LDS, 16B per lane. LDS dest must be (wave-uniform base +
// lane*16) linear; global src IS per-lane (m173) -> swizzle the source.
static __device__ __forceinline__ void gload16(const void* g, void* lds) {
  __builtin_amdgcn_global_load_lds(
      (const __attribute__((address_space(1))) unsigned int*)g,
      (__attribute__((address_space(3))) unsigned int*)(uint32_t)(uintptr_t)lds,
      16, 0, 0);
}

// ---------------------------------------------------------------------------
__global__ __launch_bounds__(256) void k_cast_bf16(const float* __restrict__ in,
                                                   unsigned short* __restrict__ out) {
  int i = blockIdx.x * 256 + threadIdx.x;
  float4 v = ((const float4*)in)[i];
  u16x4_t r = { f2bf(v.x), f2bf(v.y), f2bf(v.z), f2bf(v.w) };
  ((u16x4_t*)out)[i] = r;
}

__global__ __launch_bounds__(256) void k_transpose_cast(const float* __restrict__ W,
                                                        unsigned short* __restrict__ Wt,
                                                        int Kd, int Nd) {
  __shared__ float tile[32][33];
  int n0 = blockIdx.x * 32, k0 = blockIdx.y * 32;
  int tx = threadIdx.x, ty = threadIdx.y;
#pragma unroll
  for (int i = 0; i < 4; ++i)
    tile[ty + 8 * i][tx] = W[(size_t)(k0 + ty + 8 * i) * Nd + n0 + tx];
  __syncthreads();
#pragma unroll
  for (int i = 0; i < 4; ++i)
    Wt[(size_t)(n0 + ty + 8 * i) * Kd + k0 + tx] = f2bf(tile[tx][ty + 8 * i]);
}

// ---------------------------------------------------------------------------
// m97-structure GEMM core: 128x128 tile, BK=32, 4 waves (2x2), 4x4 frags.
static __device__ __forceinline__ void gemm128_core(
    const unsigned short* __restrict__ A, const unsigned short* __restrict__ Bt,
    int Kdim, int rowBase, int colBase,
    unsigned short* As, unsigned short* Bs, f32x4_t acc[4][4]) {
  const int tid = threadIdx.x;
  const int lane = tid & 63;
  const int wr = (tid >> 7) & 1;
  const int wc = (tid >> 6) & 1;
  const unsigned short* aSrc = A + (size_t)(rowBase + (tid >> 2)) * Kdim + (tid & 3) * 8;
  const unsigned short* bSrc = Bt + (size_t)(colBase + (tid >> 2)) * Kdim + (tid & 3) * 8;
  unsigned short* aDst0 = As + tid * 8;
  unsigned short* aDst1 = As + tid * 8 + 2048;
  unsigned short* bDst0 = Bs + tid * 8;
  unsigned short* bDst1 = Bs + tid * 8 + 2048;
  const int ar = wr * 64 + (lane & 15);
  const int br = wc * 64 + (lane & 15);
  const int kk = (lane >> 4) * 8;
  for (int k0 = 0; k0 < Kdim; k0 += 32) {
    gload16(aSrc + k0, aDst0);
    gload16(aSrc + k0 + 64 * Kdim, aDst1);
    gload16(bSrc + k0, bDst0);
    gload16(bSrc + k0 + 64 * Kdim, bDst1);
    __syncthreads();
    bf16x8_t af[4], bfr[4];
#pragma unroll
    for (int m = 0; m < 4; ++m) af[m] = *(const bf16x8_t*)&As[(ar + m * 16) * 32 + kk];
#pragma unroll
    for (int n = 0; n < 4; ++n) bfr[n] = *(const bf16x8_t*)&Bs[(br + n * 16) * 32 + kk];
#pragma unroll
    for (int m = 0; m < 4; ++m)
#pragma unroll
      for (int n = 0; n < 4; ++n)
        acc[m][n] = __builtin_amdgcn_mfma_f32_16x16x32_bf16(af[m], bfr[n], acc[m][n], 0, 0, 0);
    __syncthreads();
  }
}

// QKV GEMM. Q scaled by 0.125*log2(e) (softmax runs in base-2), V transposed.
__global__ __launch_bounds__(256) void k_gemm_qkv(
    const unsigned short* __restrict__ A, const unsigned short* __restrict__ Bt,
    const float* __restrict__ bias,
    unsigned short* __restrict__ Qo, unsigned short* __restrict__ Ko,
    unsigned short* __restrict__ Vo) {
  __shared__ alignas(16) unsigned short As[128 * 32];
  __shared__ alignas(16) unsigned short Bs[128 * 32];
  f32x4_t acc[4][4];
  f32x4_t z = {0.f, 0.f, 0.f, 0.f};
#pragma unroll
  for (int m = 0; m < 4; ++m)
#pragma unroll
    for (int n = 0; n < 4; ++n) acc[m][n] = z;
  gemm128_core(A, Bt, 1024, blockIdx.y * 128, blockIdx.x * 128, As, Bs, acc);
  const int tid = threadIdx.x, lane = tid & 63;
  const int wr = (tid >> 7) & 1, wc = (tid >> 6) & 1;
#pragma unroll
  for (int n = 0; n < 4; ++n) {
    int col = blockIdx.x * 128 + wc * 64 + n * 16 + (lane & 15);
    int which = col >> 10;                 // 0=q 1=k 2=v
    int h = (col >> 6) & 15;
    int d = col & 63;
    float bv = bias[col];
#pragma unroll
    for (int m = 0; m < 4; ++m)
#pragma unroll
      for (int r = 0; r < 4; ++r) {
        int row = blockIdx.y * 128 + wr * 64 + m * 16 + ((lane >> 4) * 4) + r;
        int b = row >> 11, t = row & 2047;
        float val = acc[m][n][r] + bv;
        if (which == 0)
          Qo[(size_t)((b * 16 + h) * 2048 + t) * 64 + d] = f2bf(val * 0.18033688011112042f);
        else if (which == 1)
          Ko[(size_t)((b * 16 + h) * 2048 + t) * 64 + d] = f2bf(val);
        else
          Vo[(size_t)((b * 16 + h) * 64 + d) * 2048 + t] = f2bf(val);
      }
  }
}

// proj GEMM: out fp32 [8192][1024] = attO_bf16 @ W_proj + b
__global__ __launch_bounds__(256) void k_gemm_proj(
    const unsigned short* __restrict__ A, const unsigned short* __restrict__ Bt,
    const float* __restrict__ bias, float* __restrict__ out) {
  __shared__ alignas(16) unsigned short As[128 * 32];
  __shared__ alignas(16) unsigned short Bs[128 * 32];
  f32x4_t acc[4][4];
  f32x4_t z = {0.f, 0.f, 0.f, 0.f};
#pragma unroll
  for (int m = 0; m < 4; ++m)
#pragma unroll
    for (int n = 0; n < 4; ++n) acc[m][n] = z;
  gemm128_core(A, Bt, 1024, blockIdx.y * 128, blockIdx.x * 128, As, Bs, acc);
  const int tid = threadIdx.x, lane = tid & 63;
  const int wr = (tid >> 7) & 1, wc = (tid >> 6) & 1;
#pragma unroll
  for (int n = 0; n < 4; ++n) {
    int col = blockIdx.x * 128 + wc * 64 + n * 16 + (lane & 15);
    float bv = bias[col];
#pragma unroll
    for (int m = 0; m < 4; ++m)
#pragma unroll
      for (int r = 0; r < 4; ++r) {
        int row = blockIdx.y * 128 + wr * 64 + m * 16 + ((lane >> 4) * 4) + r;
        out[(size_t)row * 1024 + col] = acc[m][n][r] + bv;
      }
  }
}

// ---------------------------------------------------------------------------
// causal flash attention, 32x32 swapped structure (T12).
// Block = 128 q-rows x bh; 4 waves x QBLK=32. KVBLK=64 in LDS (K [kv][d],
// V^T [d][kv], XOR-swizzled, double-buffered — staging identical to R2).
// S^T = mfma32(A=K, B=Q): lane owns q=lane&31, kv=(reg&3)+8(reg>>2)+4hi(+32tt)
// -> softmax in-register (1 shfl_xor(32) per reduce), m/l lane-local scalars.
// P -> PV B-frag: 16 cvt_pk + 8 permlane32_swap per KV-tile.
// O^T = mfma32(A=V^T, B=P): col=q stays lane-local -> rescale/normalize local.
__global__ __launch_bounds__(256) void k_attn(const unsigned short* __restrict__ Q,
                                              const unsigned short* __restrict__ K,
                                              const unsigned short* __restrict__ Vt,
                                              unsigned short* __restrict__ O) {
  __shared__ alignas(16) unsigned short KT[2][4096];  // [kv 64][d 64] swizzled
  __shared__ alignas(16) unsigned short VT[2][4096];  // [d 64][kv 64] swizzled
  const int flat = blockIdx.x;
  const int bx = 15 - (flat >> 6);       // heavy diagonal blocks first
  const int bh = flat & 63;              // same bh -> same XCD (64 % 8 == 0)
  const int tid = threadIdx.x;
  const int lane = tid & 63;
  const int w = tid >> 6;
  const int l31 = lane & 31;
  const int hi = lane >> 5;
  const int sw = l31 & 7;                // read-side XOR chunk (row&7)
  const unsigned short* Qh = Q + (size_t)bh * 2048 * 64;
  const unsigned short* Kh = K + (size_t)bh * 2048 * 64;
  const unsigned short* Vh = Vt + (size_t)bh * 64 * 2048;
  const int qrow = bx * 128 + w * 32;    // wave q-base
  const int qg = qrow + l31;             // lane's q row
  const int NT = 2 * bx + 2;             // kv tiles staged by this block

  // Q as B-frag: lane=col=q, k-window s: d = s*16 + hi*8 .. +7
  bf16x8_t qf[4];
#pragma unroll
  for (int s = 0; s < 4; ++s)
    qf[s] = *(const bf16x8_t*)&Qh[(size_t)qg * 64 + s * 16 + hi * 8];

  f32x16_t ot0 = zero16(), ot1 = zero16();  // O^T: d-tiles 0/1, col=q=l31
  float m_r = -1e30f, l_r = 0.f;

  const int srow = tid >> 3;             // staging row 0..31 (+32 second half)
  const int ssw = 8 * ((tid & 7) ^ (srow & 7));  // source-side XOR (u16)
  auto STAGE = [&](int t_, int buf_) {
#pragma unroll
    for (int i = 0; i < 2; ++i) {
      const int r_ = i * 32 + srow;
      gload16(Kh + (size_t)(t_ * 64 + r_) * 64 + ssw, &KT[buf_][i * 2048 + tid * 8]);
      gload16(Vh + (size_t)r_ * 2048 + t_ * 64 + ssw, &VT[buf_][i * 2048 + tid * 8]);
    }
  };

  STAGE(0, 0);
  __syncthreads();
  for (int t = 0; t < NT; ++t) {
    const int buf = t & 1;
    if (t + 1 < NT) STAGE(t + 1, buf ^ 1);
    if (t * 64 <= qrow + 31) {           // wave-uniform: tile intersects causal range
      // --- S^T = K Q^T : st[tt] covers kv in [64t+32tt, +32) x q ---
      f32x16_t st[2];
#pragma unroll
      for (int tt = 0; tt < 2; ++tt) {
        st[tt] = zero16();
        const unsigned short* kr = &KT[buf][(tt * 32 + l31) * 64];
#pragma unroll
        for (int s = 0; s < 4; ++s) {
          bf16x8_t kf = *(const bf16x8_t*)&kr[((2 * s + hi) ^ sw) * 8];
          st[tt] = __builtin_amdgcn_mfma_f32_32x32x16_bf16(kf, qf[s], st[tt], 0, 0, 0);
        }
      }
      // --- causal mask (diagonal tiles only) ---
      if (t * 64 + 63 > qrow) {
#pragma unroll
        for (int tt = 0; tt < 2; ++tt)
#pragma unroll
          for (int r = 0; r < 16; ++r) {
            int kv = t * 64 + tt * 32 + (r & 3) + 8 * (r >> 2) + 4 * hi;
            if (kv > qg) st[tt][r] = -1e30f;
          }
      }
      // --- online softmax, lane-local (q = l31; partner lane^32 same q) ---
      float mx = st[0][0];
#pragma unroll
      for (int tt = 0; tt < 2; ++tt)
#pragma unroll
        for (int r = 0; r < 16; ++r) mx = fmaxf(mx, st[tt][r]);
      mx = fmaxf(mx, __shfl_xor(mx, 32));
      float mnew = fmaxf(m_r, mx);
      float resc = __builtin_amdgcn_exp2f(m_r - mnew);
      float u = 0.f;
#pragma unroll
      for (int tt = 0; tt < 2; ++tt)
#pragma unroll
        for (int r = 0; r < 16; ++r) {
          float pv = __builtin_amdgcn_exp2f(st[tt][r] - mnew);
          st[tt][r] = pv;
          u += pv;
        }
      u += __shfl_xor(u, 32);
      l_r = l_r * resc + u;
      m_r = mnew;
      ot0 *= resc;
      ot1 *= resc;
      // --- P repack (cvt_pk + permlane32_swap) + PV into O^T ---
#pragma unroll
      for (int tt = 0; tt < 2; ++tt) {
        unsigned W0 = cvt_pk_bf16(st[tt][0], st[tt][1]);
        unsigned W1 = cvt_pk_bf16(st[tt][2], st[tt][3]);
        unsigned W2 = cvt_pk_bf16(st[tt][4], st[tt][5]);
        unsigned W3 = cvt_pk_bf16(st[tt][6], st[tt][7]);
        unsigned W4 = cvt_pk_bf16(st[tt][8], st[tt][9]);
        unsigned W5 = cvt_pk_bf16(st[tt][10], st[tt][11]);
        unsigned W6 = cvt_pk_bf16(st[tt][12], st[tt][13]);
        unsigned W7 = cvt_pk_bf16(st[tt][14], st[tt][15]);
        perm32swap(W0, W2);   // -> fragE.word0 / fragE.word2
        perm32swap(W1, W3);   // -> fragE.word1 / fragE.word3
        perm32swap(W4, W6);   // -> fragO.word0 / fragO.word2
        perm32swap(W5, W7);   // -> fragO.word1 / fragO.word3
        u32x4_t fe = {W0, W1, W2, W3};   // kv window 32tt + [0,16)
        u32x4_t fo = {W4, W5, W6, W7};   // kv window 32tt + [16,32)
        bf16x8_t pe = __builtin_bit_cast(bf16x8_t, fe);
        bf16x8_t po = __builtin_bit_cast(bf16x8_t, fo);
        const unsigned short* vr0 = &VT[buf][l31 * 64];         // d-tile 0
        const unsigned short* vr1 = &VT[buf][(32 + l31) * 64];  // d-tile 1
        bf16x8_t ve0 = *(const bf16x8_t*)&vr0[((4 * tt + hi) ^ sw) * 8];
        bf16x8_t vo0 = *(const bf16x8_t*)&vr0[((4 * tt + 2 + hi) ^ sw) * 8];
        bf16x8_t ve1 = *(const bf16x8_t*)&vr1[((4 * tt + hi) ^ sw) * 8];
        bf16x8_t vo1 = *(const bf16x8_t*)&vr1[((4 * tt + 2 + hi) ^ sw) * 8];
        ot0 = __builtin_amdgcn_mfma_f32_32x32x16_bf16(ve0, pe, ot0, 0, 0, 0);
        ot0 = __builtin_amdgcn_mfma_f32_32x32x16_bf16(vo0, po, ot0, 0, 0, 0);
        ot1 = __builtin_amdgcn_mfma_f32_32x32x16_bf16(ve1, pe, ot1, 0, 0, 0);
        ot1 = __builtin_amdgcn_mfma_f32_32x32x16_bf16(vo1, po, ot1, 0, 0, 0);
      }
    }
    __syncthreads();
  }
  // --- epilogue: O^T lane-local normalize, write O (B,T,C) bf16 ---
  const float inv = 1.0f / l_r;
  const int b = bh >> 4, h = bh & 15;
  unsigned short* orow = O + (size_t)(b * 2048 + qg) * 1024 + h * 64;
#pragma unroll
  for (int m = 0; m < 4; ++m) {          // d = 8m + 4hi + {0..3} (+32 for ot1)
    u16x4_t r0, r1;
#pragma unroll
    for (int j = 0; j < 4; ++j) {
      r0[j] = f2bf(ot0[4 * m + j] * inv);
      r1[j] = f2bf(ot1[4 * m + j] * inv);
    }
    *(u16x4_t*)&orow[8 * m + 4 * hi] = r0;
    *(u16x4_t*)&orow[32 + 8 * m + 4 * hi] = r1;
  }
}

// ---------------------------------------------------------------------------
extern "C" void kernel_launch(void* const* d_in, const int* in_sizes, int n_in,
                              void* d_out, int out_size, void* d_ws, size_t ws_size,
                              hipStream_t stream) {
  const float* x     = (const float*)d_in[0];
  const float* Wqkv  = (const float*)d_in[1];
  const float* bqkv  = (const float*)d_in[2];
  const float* Wproj = (const float*)d_in[3];
  const float* bproj = (const float*)d_in[4];
  float* out = (float*)d_out;

  char* ws = (char*)d_ws;
  unsigned short* xb     = (unsigned short*)(ws);                    // 16 MiB
  unsigned short* wqkvT  = (unsigned short*)(ws + 16777216);         // 6 MiB
  unsigned short* wprojT = (unsigned short*)(ws + 23068672);         // 2 MiB
  unsigned short* Qb     = (unsigned short*)(ws + 25165824);         // 16 MiB (B,H,T,D) *0.125*log2e
  unsigned short* Kb     = (unsigned short*)(ws + 41943040);         // 16 MiB (B,H,T,D)
  unsigned short* Vb     = (unsigned short*)(ws + 58720256);         // 16 MiB (B,H,D,T) transposed
  unsigned short* Ob     = (unsigned short*)(ws + 75497472);         // 16 MiB (B,T,C)

  k_cast_bf16<<<8192, 256, 0, stream>>>(x, xb);
  k_transpose_cast<<<dim3(96, 32), dim3(32, 8), 0, stream>>>(Wqkv, wqkvT, 1024, 3072);
  k_transpose_cast<<<dim3(32, 32), dim3(32, 8), 0, stream>>>(Wproj, wprojT, 1024, 1024);
  k_gemm_qkv<<<dim3(24, 64), 256, 0, stream>>>(xb, wqkvT, bqkv, Qb, Kb, Vb);
  k_attn<<<1024, 256, 0, stream>>>(Qb, Kb, Vb, Ob);
  k_gemm_proj<<<dim3(8, 64), 256, 0, stream>>>(Ob, wprojT, bproj, out);
}

// Round 7
// 271.421 us; speedup vs baseline: 1.9965x; 1.0638x over previous
//
#include <hip/hip_runtime.h>
#include <stdint.h>

// ---------------------------------------------------------------------------
// CausalSelfAttention (B=4, T=2048, C=1024, H=16, D=64) on gfx950.
// cast x->bf16; transpose W's to [N][K] bf16; QKV GEMM (128x256 dbuf-pipelined
// bf16 MFMA, T2-swizzled LDS, raw-barrier counted schedule) writing
// Q*0.125*log2e (B,H,T,D), K (B,H,T,D), V transposed (B,H,D,T); causal flash
// attention (32x32 swapped-QK^T, in-register softmax); proj GEMM (same core).
// ---------------------------------------------------------------------------

typedef __attribute__((ext_vector_type(8))) __bf16 bf16x8_t;   // MFMA A/B frag
typedef __attribute__((ext_vector_type(4))) float f32x4_t;     // 16x16 C/D
typedef __attribute__((ext_vector_type(16))) float f32x16_t;   // 32x32 C/D
typedef __attribute__((ext_vector_type(4))) unsigned short u16x4_t;
typedef __attribute__((ext_vector_type(4))) unsigned int u32x4_t;

static __device__ __forceinline__ unsigned short f2bf(float f) {
  union { float f; unsigned u; } c; c.f = f;
  unsigned r = c.u + 0x7FFFu + ((c.u >> 16) & 1u);  // RNE
  return (unsigned short)(r >> 16);
}

static __device__ __forceinline__ unsigned cvt_pk_bf16(float lo, float hi) {
  unsigned r;
  asm volatile("v_cvt_pk_bf16_f32 %0, %1, %2" : "=v"(r) : "v"(lo), "v"(hi));
  return r;
}

// v_permlane32_swap_b32 a,b : a.hi32lanes <-> b.lo32lanes (both updated)
static __device__ __forceinline__ void perm32swap(unsigned& a, unsigned& b) {
  asm volatile("v_permlane32_swap_b32 %0, %1" : "+v"(a), "+v"(b));
}

static __device__ __forceinline__ f32x16_t zero16() {
  f32x16_t v;
#pragma unroll
  for (int i = 0; i < 16; ++i) v[i] = 0.f;
  return v;
}

// async global->LDS, 16B per lane. LDS dest must be (wave-uniform base +
// lane*16) linear; global src IS per-lane (m173) -> swizzle the source.
static __device__ __forceinline__ void gload16(const void* g, void* lds) {
  __builtin_amdgcn_global_load_lds(
      (const __attribute__((address_space(1))) unsigned int*)g,
      (__attribute__((address_space(3))) unsigned int*)(uint32_t)(uintptr_t)lds,
      16, 0, 0);
}

// ---------------------------------------------------------------------------
__global__ __launch_bounds__(256) void k_cast_bf16(const float* __restrict__ in,
                                                   unsigned short* __restrict__ out) {
  int i = blockIdx.x * 256 + threadIdx.x;
  float4 v = ((const float4*)in)[i];
  u16x4_t r = { f2bf(v.x), f2bf(v.y), f2bf(v.z), f2bf(v.w) };
  ((u16x4_t*)out)[i] = r;
}

__global__ __launch_bounds__(256) void k_transpose_cast(const float* __restrict__ W,
                                                        unsigned short* __restrict__ Wt,
                                                        int Kd, int Nd) {
  __shared__ float tile[32][33];
  int n0 = blockIdx.x * 32, k0 = blockIdx.y * 32;
  int tx = threadIdx.x, ty = threadIdx.y;
#pragma unroll
  for (int i = 0; i < 4; ++i)
    tile[ty + 8 * i][tx] = W[(size_t)(k0 + ty + 8 * i) * Nd + n0 + tx];
  __syncthreads();
#pragma unroll
  for (int i = 0; i < 4; ++i)
    Wt[(size_t)(n0 + ty + 8 * i) * Kd + k0 + tx] = f2bf(tile[tx][ty + 8 * i]);
}

// ---------------------------------------------------------------------------
// Pipelined GEMM core: 128x256 tile, BK=64, 8 waves (2x4), per-wave C 64x64.
// Double-buffered LDS (A[2][128][64], B[2][256][64] u16, 96 KiB) with T2
// XOR-swizzle (chunk ^= row&7; inverse pre-applied on global source, linear
// gload_lds dest — rule #21 both-sides pattern, 0-conflict-verified in attn).
// Schedule per K-tile: issue 6 gload16 for tile k+1 -> compute tile k
// (16 ds_read_b128 + 32 MFMA) -> s_waitcnt vmcnt(0) -> raw s_barrier.
// One barrier/K-tile; staged loads covered by ~64 MFMA of compute.
static __device__ __forceinline__ void gemm_core(
    const unsigned short* __restrict__ A, const unsigned short* __restrict__ Bt,
    int Kd, int bm0, int bn0,
    unsigned short (*As)[128 * 64], unsigned short (*Bs)[256 * 64],
    f32x4_t acc[4][4]) {
  const int tid = threadIdx.x;
  const int lane = tid & 63;
  const int wid = tid >> 6;
  const int wm = wid >> 2, wn = wid & 3;
  const int l15 = lane & 15, lhi = lane >> 4;
  const int trow = tid >> 3;                       // 0..63
  const int schunk = ((tid & 7) ^ (trow & 7)) * 8; // inverse swizzle (u16)
  const unsigned short* aS = A + (size_t)(bm0 + trow) * Kd + schunk;
  const unsigned short* bS = Bt + (size_t)(bn0 + trow) * Kd + schunk;
  const int NK = Kd >> 6;

  auto STAGE = [&](int kt, int sl) {
    const size_t ko = (size_t)kt * 64;
#pragma unroll
    for (int j = 0; j < 2; ++j)                    // A: 128 rows
      gload16(aS + ko + (size_t)(64 * j) * Kd, &As[sl][j * 4096 + tid * 8]);
#pragma unroll
    for (int j = 0; j < 4; ++j)                    // B: 256 rows
      gload16(bS + ko + (size_t)(64 * j) * Kd, &Bs[sl][j * 4096 + tid * 8]);
  };

  STAGE(0, 0);
  asm volatile("s_waitcnt vmcnt(0)" ::: "memory");
  __builtin_amdgcn_s_barrier();
  __builtin_amdgcn_sched_barrier(0);
  for (int kt = 0; kt < NK; ++kt) {
    const int sl = kt & 1;
    if (kt + 1 < NK) STAGE(kt + 1, sl ^ 1);        // prefetch next K-tile
    __builtin_amdgcn_sched_barrier(0);             // keep issue-early
#pragma unroll
    for (int ks = 0; ks < 2; ++ks) {
      const int ch = ((4 * ks + lhi) ^ (l15 & 7)) * 8;  // swizzled read chunk
      bf16x8_t af[4], bfr[4];
#pragma unroll
      for (int m = 0; m < 4; ++m)
        af[m] = *(const bf16x8_t*)&As[sl][(wm * 64 + m * 16 + l15) * 64 + ch];
#pragma unroll
      for (int n = 0; n < 4; ++n)
        bfr[n] = *(const bf16x8_t*)&Bs[sl][(wn * 64 + n * 16 + l15) * 64 + ch];
#pragma unroll
      for (int m = 0; m < 4; ++m)
#pragma unroll
        for (int n = 0; n < 4; ++n)
          acc[m][n] = __builtin_amdgcn_mfma_f32_16x16x32_bf16(af[m], bfr[n], acc[m][n], 0, 0, 0);
    }
    asm volatile("s_waitcnt vmcnt(0)" ::: "memory");  // staged tile landed
    __builtin_amdgcn_s_barrier();                     // raw: no full drain
    __builtin_amdgcn_sched_barrier(0);
  }
}

// QKV GEMM. Q scaled by 0.125*log2(e) (softmax runs in base-2), V transposed.
// grid 768 = 64 row-tiles x 12 col-tiles (3 exact CU rounds), XCD-swizzled.
__global__ __launch_bounds__(512, 2) void k_gemm_qkv(
    const unsigned short* __restrict__ A, const unsigned short* __restrict__ Bt,
    const float* __restrict__ bias,
    unsigned short* __restrict__ Qo, unsigned short* __restrict__ Ko,
    unsigned short* __restrict__ Vo) {
  __shared__ alignas(16) unsigned short As[2][128 * 64];
  __shared__ alignas(16) unsigned short Bs[2][256 * 64];
  const int orig = blockIdx.x;
  const int swz = (orig & 7) * 96 + (orig >> 3);   // 768/8 = 96, bijective
  const int by = swz / 12, bx = swz % 12;
  f32x4_t acc[4][4];
  f32x4_t z = {0.f, 0.f, 0.f, 0.f};
#pragma unroll
  for (int m = 0; m < 4; ++m)
#pragma unroll
    for (int n = 0; n < 4; ++n) acc[m][n] = z;
  gemm_core(A, Bt, 1024, by * 128, bx * 256, As, Bs, acc);
  const int tid = threadIdx.x, lane = tid & 63;
  const int wid = tid >> 6, wm = wid >> 2, wn = wid & 3;
  const int l15 = lane & 15, lhi = lane >> 4;
#pragma unroll
  for (int n = 0; n < 4; ++n) {
    int col = bx * 256 + wn * 64 + n * 16 + l15;
    int which = col >> 10;                 // 0=q 1=k 2=v
    int h = (col >> 6) & 15;
    int d = col & 63;
    float bv = bias[col];
#pragma unroll
    for (int m = 0; m < 4; ++m)
#pragma unroll
      for (int r = 0; r < 4; ++r) {
        int row = by * 128 + wm * 64 + m * 16 + lhi * 4 + r;
        int b = row >> 11, t = row & 2047;
        float val = acc[m][n][r] + bv;
        if (which == 0)
          Qo[(size_t)((b * 16 + h) * 2048 + t) * 64 + d] = f2bf(val * 0.18033688011112042f);
        else if (which == 1)
          Ko[(size_t)((b * 16 + h) * 2048 + t) * 64 + d] = f2bf(val);
        else
          Vo[(size_t)((b * 16 + h) * 64 + d) * 2048 + t] = f2bf(val);
      }
  }
}

// proj GEMM: out fp32 [8192][1024]. grid 256 = 64 x 4 (1 exact CU round).
__global__ __launch_bounds__(512, 2) void k_gemm_proj(
    const unsigned short* __restrict__ A, const unsigned short* __restrict__ Bt,
    const float* __restrict__ bias, float* __restrict__ out) {
  __shared__ alignas(16) unsigned short As[2][128 * 64];
  __shared__ alignas(16) unsigned short Bs[2][256 * 64];
  const int orig = blockIdx.x;
  const int swz = (orig & 7) * 32 + (orig >> 3);   // 256/8 = 32, bijective
  const int by = swz >> 2, bx = swz & 3;
  f32x4_t acc[4][4];
  f32x4_t z = {0.f, 0.f, 0.f, 0.f};
#pragma unroll
  for (int m = 0; m < 4; ++m)
#pragma unroll
    for (int n = 0; n < 4; ++n) acc[m][n] = z;
  gemm_core(A, Bt, 1024, by * 128, bx * 256, As, Bs, acc);
  const int tid = threadIdx.x, lane = tid & 63;
  const int wid = tid >> 6, wm = wid >> 2, wn = wid & 3;
  const int l15 = lane & 15, lhi = lane >> 4;
#pragma unroll
  for (int n = 0; n < 4; ++n) {
    int col = bx * 256 + wn * 64 + n * 16 + l15;
    float bv = bias[col];
#pragma unroll
    for (int m = 0; m < 4; ++m)
#pragma unroll
      for (int r = 0; r < 4; ++r) {
        int row = by * 128 + wm * 64 + m * 16 + lhi * 4 + r;
        out[(size_t)row * 1024 + col] = acc[m][n][r] + bv;
      }
  }
}

// ---------------------------------------------------------------------------
// causal flash attention, 32x32 swapped structure (T12) — unchanged from R4.
__global__ __launch_bounds__(256) void k_attn(const unsigned short* __restrict__ Q,
                                              const unsigned short* __restrict__ K,
                                              const unsigned short* __restrict__ Vt,
                                              unsigned short* __restrict__ O) {
  __shared__ alignas(16) unsigned short KT[2][4096];  // [kv 64][d 64] swizzled
  __shared__ alignas(16) unsigned short VT[2][4096];  // [d 64][kv 64] swizzled
  const int flat = blockIdx.x;
  const int bx = 15 - (flat >> 6);       // heavy diagonal blocks first
  const int bh = flat & 63;              // same bh -> same XCD (64 % 8 == 0)
  const int tid = threadIdx.x;
  const int lane = tid & 63;
  const int w = tid >> 6;
  const int l31 = lane & 31;
  const int hi = lane >> 5;
  const int sw = l31 & 7;                // read-side XOR chunk (row&7)
  const unsigned short* Qh = Q + (size_t)bh * 2048 * 64;
  const unsigned short* Kh = K + (size_t)bh * 2048 * 64;
  const unsigned short* Vh = Vt + (size_t)bh * 64 * 2048;
  const int qrow = bx * 128 + w * 32;    // wave q-base
  const int qg = qrow + l31;             // lane's q row
  const int NT = 2 * bx + 2;             // kv tiles staged by this block

  bf16x8_t qf[4];
#pragma unroll
  for (int s = 0; s < 4; ++s)
    qf[s] = *(const bf16x8_t*)&Qh[(size_t)qg * 64 + s * 16 + hi * 8];

  f32x16_t ot0 = zero16(), ot1 = zero16();  // O^T: d-tiles 0/1, col=q=l31
  float m_r = -1e30f, l_r = 0.f;

  const int srow = tid >> 3;             // staging row 0..31 (+32 second half)
  const int ssw = 8 * ((tid & 7) ^ (srow & 7));  // source-side XOR (u16)
  auto STAGE = [&](int t_, int buf_) {
#pragma unroll
    for (int i = 0; i < 2; ++i) {
      const int r_ = i * 32 + srow;
      gload16(Kh + (size_t)(t_ * 64 + r_) * 64 + ssw, &KT[buf_][i * 2048 + tid * 8]);
      gload16(Vh + (size_t)r_ * 2048 + t_ * 64 + ssw, &VT[buf_][i * 2048 + tid * 8]);
    }
  };

  STAGE(0, 0);
  __syncthreads();
  for (int t = 0; t < NT; ++t) {
    const int buf = t & 1;
    if (t + 1 < NT) STAGE(t + 1, buf ^ 1);
    if (t * 64 <= qrow + 31) {           // wave-uniform: tile intersects causal range
      f32x16_t st[2];
#pragma unroll
      for (int tt = 0; tt < 2; ++tt) {
        st[tt] = zero16();
        const unsigned short* kr = &KT[buf][(tt * 32 + l31) * 64];
#pragma unroll
        for (int s = 0; s < 4; ++s) {
          bf16x8_t kf = *(const bf16x8_t*)&kr[((2 * s + hi) ^ sw) * 8];
          st[tt] = __builtin_amdgcn_mfma_f32_32x32x16_bf16(kf, qf[s], st[tt], 0, 0, 0);
        }
      }
      if (t * 64 + 63 > qrow) {
#pragma unroll
        for (int tt = 0; tt < 2; ++tt)
#pragma unroll
          for (int r = 0; r < 16; ++r) {
            int kv = t * 64 + tt * 32 + (r & 3) + 8 * (r >> 2) + 4 * hi;
            if (kv > qg) st[tt][r] = -1e30f;
          }
      }
      float mx = st[0][0];
#pragma unroll
      for (int tt = 0; tt < 2; ++tt)
#pragma unroll
        for (int r = 0; r < 16; ++r) mx = fmaxf(mx, st[tt][r]);
      mx = fmaxf(mx, __shfl_xor(mx, 32));
      float mnew = fmaxf(m_r, mx);
      float resc = __builtin_amdgcn_exp2f(m_r - mnew);
      float u = 0.f;
#pragma unroll
      for (int tt = 0; tt < 2; ++tt)
#pragma unroll
        for (int r = 0; r < 16; ++r) {
          float pv = __builtin_amdgcn_exp2f(st[tt][r] - mnew);
          st[tt][r] = pv;
          u += pv;
        }
      u += __shfl_xor(u, 32);
      l_r = l_r * resc + u;
      m_r = mnew;
      ot0 *= resc;
      ot1 *= resc;
#pragma unroll
      for (int tt = 0; tt < 2; ++tt) {
        unsigned W0 = cvt_pk_bf16(st[tt][0], st[tt][1]);
        unsigned W1 = cvt_pk_bf16(st[tt][2], st[tt][3]);
        unsigned W2 = cvt_pk_bf16(st[tt][4], st[tt][5]);
        unsigned W3 = cvt_pk_bf16(st[tt][6], st[tt][7]);
        unsigned W4 = cvt_pk_bf16(st[tt][8], st[tt][9]);
        unsigned W5 = cvt_pk_bf16(st[tt][10], st[tt][11]);
        unsigned W6 = cvt_pk_bf16(st[tt][12], st[tt][13]);
        unsigned W7 = cvt_pk_bf16(st[tt][14], st[tt][15]);
        perm32swap(W0, W2);
        perm32swap(W1, W3);
        perm32swap(W4, W6);
        perm32swap(W5, W7);
        u32x4_t fe = {W0, W1, W2, W3};   // kv window 32tt + [0,16)
        u32x4_t fo = {W4, W5, W6, W7};   // kv window 32tt + [16,32)
        bf16x8_t pe = __builtin_bit_cast(bf16x8_t, fe);
        bf16x8_t po = __builtin_bit_cast(bf16x8_t, fo);
        const unsigned short* vr0 = &VT[buf][l31 * 64];         // d-tile 0
        const unsigned short* vr1 = &VT[buf][(32 + l31) * 64];  // d-tile 1
        bf16x8_t ve0 = *(const bf16x8_t*)&vr0[((4 * tt + hi) ^ sw) * 8];
        bf16x8_t vo0 = *(const bf16x8_t*)&vr0[((4 * tt + 2 + hi) ^ sw) * 8];
        bf16x8_t ve1 = *(const bf16x8_t*)&vr1[((4 * tt + hi) ^ sw) * 8];
        bf16x8_t vo1 = *(const bf16x8_t*)&vr1[((4 * tt + 2 + hi) ^ sw) * 8];
        ot0 = __builtin_amdgcn_mfma_f32_32x32x16_bf16(ve0, pe, ot0, 0, 0, 0);
        ot0 = __builtin_amdgcn_mfma_f32_32x32x16_bf16(vo0, po, ot0, 0, 0, 0);
        ot1 = __builtin_amdgcn_mfma_f32_32x32x16_bf16(ve1, pe, ot1, 0, 0, 0);
        ot1 = __builtin_amdgcn_mfma_f32_32x32x16_bf16(vo1, po, ot1, 0, 0, 0);
      }
    }
    __syncthreads();
  }
  const float inv = 1.0f / l_r;
  const int b = bh >> 4, h = bh & 15;
  unsigned short* orow = O + (size_t)(b * 2048 + qg) * 1024 + h * 64;
#pragma unroll
  for (int m = 0; m < 4; ++m) {          // d = 8m + 4hi + {0..3} (+32 for ot1)
    u16x4_t r0, r1;
#pragma unroll
    for (int j = 0; j < 4; ++j) {
      r0[j] = f2bf(ot0[4 * m + j] * inv);
      r1[j] = f2bf(ot1[4 * m + j] * inv);
    }
    *(u16x4_t*)&orow[8 * m + 4 * hi] = r0;
    *(u16x4_t*)&orow[32 + 8 * m + 4 * hi] = r1;
  }
}

// ---------------------------------------------------------------------------
extern "C" void kernel_launch(void* const* d_in, const int* in_sizes, int n_in,
                              void* d_out, int out_size, void* d_ws, size_t ws_size,
                              hipStream_t stream) {
  const float* x     = (const float*)d_in[0];
  const float* Wqkv  = (const float*)d_in[1];
  const float* bqkv  = (const float*)d_in[2];
  const float* Wproj = (const float*)d_in[3];
  const float* bproj = (const float*)d_in[4];
  float* out = (float*)d_out;

  char* ws = (char*)d_ws;
  unsigned short* xb     = (unsigned short*)(ws);                    // 16 MiB
  unsigned short* wqkvT  = (unsigned short*)(ws + 16777216);         // 6 MiB
  unsigned short* wprojT = (unsigned short*)(ws + 23068672);         // 2 MiB
  unsigned short* Qb     = (unsigned short*)(ws + 25165824);         // 16 MiB (B,H,T,D) *0.125*log2e
  unsigned short* Kb     = (unsigned short*)(ws + 41943040);         // 16 MiB (B,H,T,D)
  unsigned short* Vb     = (unsigned short*)(ws + 58720256);         // 16 MiB (B,H,D,T) transposed
  unsigned short* Ob     = (unsigned short*)(ws + 75497472);         // 16 MiB (B,T,C)

  k_cast_bf16<<<8192, 256, 0, stream>>>(x, xb);
  k_transpose_cast<<<dim3(96, 32), dim3(32, 8), 0, stream>>>(Wqkv, wqkvT, 1024, 3072);
  k_transpose_cast<<<dim3(32, 32), dim3(32, 8), 0, stream>>>(Wproj, wprojT, 1024, 1024);
  k_gemm_qkv<<<768, 512, 0, stream>>>(xb, wqkvT, bqkv, Qb, Kb, Vb);
  k_attn<<<1024, 256, 0, stream>>>(Qb, Kb, Vb, Ob);
  k_gemm_proj<<<256, 512, 0, stream>>>(Ob, wprojT, bproj, out);
}